// Round 18
// baseline (15513.377 us; speedup 1.0000x reference)
//
#include <hip/hip_runtime.h>
#include <math.h>

#define TT 2048
#define II 128
#define NN 1024
#define NWG 128        // 64 i-blocks x 2 chain-pairs (half-grid; latency-bound)
#define NTHR 512

#define SW(k) ((k) ^ ((((k) >> 4) & 7) << 2))

// R18: two independent 8-batch chains per WG, R15's proven 16-row body run
// twice per step (phase A = chain 2p, phase B = chain 2p+1). Chain B's
// pointers are chain A's plus COMPILE-TIME constant offsets (+8*TT*II u,
// +8*TT*NN h/out), computed transiently -> persistent register set is
// bit-identical to R15's measured 116 VGPR (R17's failure class: ~26 extra
// persistent pointer regs + cross-phase uv liveness around inline-asm loads).
// One shared h_stage: S2A orders all A-QSTEP reads before B's staging;
// S2B(t-1) orders B-reads before A's staging(t). Per-chain sync = R15's tail
// VERBATIM (drain -> S2 -> tid0 signal; poll >= t -> sc1 loads) -- R16 proved
// that tail is load-bearing. Steady state: each chain's producers signaled
// one half-cycle (~2us) before the consumer polls -> poll finds flags set,
// sync round-trip hides under the other chain's phase.

__device__ __forceinline__ float dpp_add_xor1(float x) {  // quad_perm [1,0,3,2]
    int y = __builtin_amdgcn_update_dpp(0, __float_as_int(x), 0xB1, 0xF, 0xF, true);
    return x + __int_as_float(y);
}
__device__ __forceinline__ float dpp_add_xor2(float x) {  // quad_perm [2,3,0,1]
    int y = __builtin_amdgcn_update_dpp(0, __float_as_int(x), 0x4E, 0xF, 0xF, true);
    return x + __int_as_float(y);
}
__device__ __forceinline__ float dpp_add_xor8(float x) {  // row_ror:8 (xor8 in row16)
    int y = __builtin_amdgcn_update_dpp(0, __float_as_int(x), 0x128, 0xF, 0xF, true);
    return x + __int_as_float(y);
}

__global__ __launch_bounds__(NTHR)
__attribute__((amdgpu_waves_per_eu(2, 2)))
void esn_kernel(const float* __restrict__ u, const float* __restrict__ w_in,
                const float* __restrict__ w, const float* __restrict__ w_bias,
                float* __restrict__ out, unsigned int* __restrict__ flags)
{
    __shared__ alignas(16) float w_lds[16 * 1024];   // 64 KB, swizzled, static
    __shared__ alignas(16) float h_stage[8 * 1024];  // 32 KB, shared by phases

    const int tid = threadIdx.x;
    const int wg  = blockIdx.x;
    const int ig  = wg & 63;
    const int p   = wg >> 6;             // chain pair: chains 2p, 2p+1
    const int l   = tid & 63;
    const int rt  = (tid >> 6) & 3;
    const int bt  = tid >> 8;            // 0..1
    const int n0  = ig * 16 + rt * 4;
    const int bgb = (2 * p) * 8 + bt * 4;          // chain A batch base

    const size_t UOFF = (size_t)8 * TT * II;       // chain B = chain A + 8 batches
    const size_t HOFF = (size_t)8 * TT * NN;

    // ---- stage W tile into LDS once (coalesced global, swizzled LDS) ----
    #pragma unroll
    for (int c = 0; c < 32; ++c) {
        int idx = c * NTHR + tid;        // 0..16383
        int row = idx >> 10;
        int k   = idx & 1023;
        w_lds[row * 1024 + SW(k)] = w[(size_t)(ig * 16 + row) * NN + k];
    }

    // W_in slice (2 floats/row) + bias, in registers
    float2 wir0 = *reinterpret_cast<const float2*>(w_in + (n0 + 0) * II + 2 * l);
    float2 wir1 = *reinterpret_cast<const float2*>(w_in + (n0 + 1) * II + 2 * l);
    float2 wir2 = *reinterpret_cast<const float2*>(w_in + (n0 + 2) * II + 2 * l);
    float2 wir3 = *reinterpret_cast<const float2*>(w_in + (n0 + 3) * II + 2 * l);
    const float b0 = w_bias[n0 + 0];
    const float b1 = w_bias[n0 + 1];
    const float b2 = w_bias[n0 + 2];
    const float b3 = w_bias[n0 + 3];

    // chain-A walking pointers (R15's exact persistent set)
    const float* up0 = u + (size_t)(bgb + 0) * TT * II + 2 * l;
    const float* up1 = u + (size_t)(bgb + 1) * TT * II + 2 * l;
    const float* up2 = u + (size_t)(bgb + 2) * TT * II + 2 * l;
    const float* up3 = u + (size_t)(bgb + 3) * TT * II + 2 * l;

    const float *hp0, *hp1, *hp2, *hp3;
    int hw0, hw1, hw2, hw3;
    {
        int f4, bl, k4;
        f4 = 0 * NTHR + tid; bl = f4 >> 8; k4 = f4 & 255;
        hp0 = out + (size_t)((2 * p) * 8 + bl) * TT * NN + 4 * k4 - NN;
        hw0 = bl * 1024 + SW(4 * k4);
        f4 = 1 * NTHR + tid; bl = f4 >> 8; k4 = f4 & 255;
        hp1 = out + (size_t)((2 * p) * 8 + bl) * TT * NN + 4 * k4 - NN;
        hw1 = bl * 1024 + SW(4 * k4);
        f4 = 2 * NTHR + tid; bl = f4 >> 8; k4 = f4 & 255;
        hp2 = out + (size_t)((2 * p) * 8 + bl) * TT * NN + 4 * k4 - NN;
        hw2 = bl * 1024 + SW(4 * k4);
        f4 = 3 * NTHR + tid; bl = f4 >> 8; k4 = f4 & 255;
        hp3 = out + (size_t)((2 * p) * 8 + bl) * TT * NN + 4 * k4 - NN;
        hw3 = bl * 1024 + SW(4 * k4);
    }

    // per-lane swizzled read offsets: SW applied to the FULL index (R6/R9 lesson)
    const int kl = 16 * l;
    const int o0 = SW(kl + 0);
    const int o1 = SW(kl + 4);
    const int o2 = SW(kl + 8);
    const int o3 = SW(kl + 12);
    const int wb = rt * 4 * 1024;
    const int hb = bt * 4 * 1024;

    unsigned int* gfA = flags + (2 * p) * 64;       // 64 producers per chain
    unsigned int* gfB = flags + (2 * p + 1) * 64;

    __syncthreads();   // w_lds ready

#define UPART(acc, bb, uv) \
    acc[0][bb] = wir0.x * uv.x + wir0.y * uv.y; \
    acc[1][bb] = wir1.x * uv.x + wir1.y * uv.y; \
    acc[2][bb] = wir2.x * uv.x + wir2.y * uv.y; \
    acc[3][bb] = wir3.x * uv.x + wir3.y * uv.y;

#define DOT(acc, rr, bb, wv, hv) \
    acc[rr][bb] += wv.x*hv.x + wv.y*hv.y + wv.z*hv.z + wv.w*hv.w;

#define QSTEP(acc, o) { \
    float4 wv0 = *reinterpret_cast<const float4*>(&w_lds[wb + 0*1024 + (o)]); \
    float4 wv1 = *reinterpret_cast<const float4*>(&w_lds[wb + 1*1024 + (o)]); \
    float4 wv2 = *reinterpret_cast<const float4*>(&w_lds[wb + 2*1024 + (o)]); \
    float4 wv3 = *reinterpret_cast<const float4*>(&w_lds[wb + 3*1024 + (o)]); \
    float4 hv0 = *reinterpret_cast<const float4*>(&h_stage[hb + 0*1024 + (o)]); \
    float4 hv1 = *reinterpret_cast<const float4*>(&h_stage[hb + 1*1024 + (o)]); \
    float4 hv2 = *reinterpret_cast<const float4*>(&h_stage[hb + 2*1024 + (o)]); \
    float4 hv3 = *reinterpret_cast<const float4*>(&h_stage[hb + 3*1024 + (o)]); \
    DOT(acc,0,0,wv0,hv0) DOT(acc,1,0,wv1,hv0) DOT(acc,2,0,wv2,hv0) DOT(acc,3,0,wv3,hv0) \
    DOT(acc,0,1,wv0,hv1) DOT(acc,1,1,wv1,hv1) DOT(acc,2,1,wv2,hv1) DOT(acc,3,1,wv3,hv1) \
    DOT(acc,0,2,wv0,hv2) DOT(acc,1,2,wv1,hv2) DOT(acc,2,2,wv2,hv2) DOT(acc,3,2,wv3,hv2) \
    DOT(acc,0,3,wv0,hv3) DOT(acc,1,3,wv1,hv3) DOT(acc,2,3,wv2,hv3) DOT(acc,3,3,wv3,hv3) }

// One full R15 step body for one chain. GF = flag array; UOF/HOF = 0 (chain A)
// or UOFF/HOFF (chain B); BGB = batch base for the output store.
#define PHASE(GF, UOF, HOF, BGB) { \
    float2 uv0, uv1, uv2, uv3; \
    { \
        const float* a0 = up0 + (UOF); \
        const float* a1 = up1 + (UOF); \
        const float* a2 = up2 + (UOF); \
        const float* a3 = up3 + (UOF); \
        asm volatile("global_load_dwordx2 %0, %1, off" : "=v"(uv0) : "v"(a0)); \
        asm volatile("global_load_dwordx2 %0, %1, off" : "=v"(uv1) : "v"(a1)); \
        asm volatile("global_load_dwordx2 %0, %1, off" : "=v"(uv2) : "v"(a2)); \
        asm volatile("global_load_dwordx2 %0, %1, off" : "=v"(uv3) : "v"(a3)); \
    } \
    float4 h0, h1, h2, h3; \
    if (t > 0) { \
        for (;;) { \
            unsigned int v = __hip_atomic_load(&(GF)[l], __ATOMIC_RELAXED, \
                                               __HIP_MEMORY_SCOPE_AGENT); \
            if (__all((int)(v >= (unsigned)t))) break; \
            __builtin_amdgcn_s_sleep(1); \
        } \
        asm volatile("" ::: "memory"); \
        { \
            const float* q0 = hp0 + (HOF); \
            const float* q1 = hp1 + (HOF); \
            const float* q2 = hp2 + (HOF); \
            const float* q3 = hp3 + (HOF); \
            asm volatile("global_load_dwordx4 %0, %1, off sc1" : "=v"(h0) : "v"(q0)); \
            asm volatile("global_load_dwordx4 %0, %1, off sc1" : "=v"(h1) : "v"(q1)); \
            asm volatile("global_load_dwordx4 %0, %1, off sc1" : "=v"(h2) : "v"(q2)); \
            asm volatile("global_load_dwordx4 %0, %1, off sc1" : "=v"(h3) : "v"(q3)); \
        } \
        asm volatile("s_waitcnt vmcnt(4)" ::: "memory"); \
        __builtin_amdgcn_sched_barrier(0); \
    } else { \
        asm volatile("s_waitcnt vmcnt(0)" ::: "memory"); \
        __builtin_amdgcn_sched_barrier(0); \
    } \
    float acc[4][4]; \
    UPART(acc, 0, uv0) UPART(acc, 1, uv1) UPART(acc, 2, uv2) UPART(acc, 3, uv3) \
    if (t > 0) { \
        asm volatile("s_waitcnt vmcnt(0)" ::: "memory"); \
        __builtin_amdgcn_sched_barrier(0); \
        *reinterpret_cast<float4*>(&h_stage[hw0]) = h0; \
        *reinterpret_cast<float4*>(&h_stage[hw1]) = h1; \
        *reinterpret_cast<float4*>(&h_stage[hw2]) = h2; \
        *reinterpret_cast<float4*>(&h_stage[hw3]) = h3; \
    } \
    __syncthreads();   /* S1b: staging visible */ \
    if (t > 0) { \
        QSTEP(acc, o0) QSTEP(acc, o1) QSTEP(acc, o2) QSTEP(acc, o3) \
    } \
    _Pragma("unroll") \
    for (int rr = 0; rr < 4; ++rr) \
        _Pragma("unroll") \
        for (int bb = 0; bb < 4; ++bb) { \
            float a = acc[rr][bb]; \
            a = dpp_add_xor1(a); \
            a = dpp_add_xor2(a); \
            a += __shfl_xor(a, 4); \
            a = dpp_add_xor8(a); \
            acc[rr][bb] = a; \
        } \
    { \
        const int m = l & 15; \
        float c00 = (m & 1) ? acc[1][0] : acc[0][0]; \
        float c01 = (m & 1) ? acc[3][0] : acc[2][0]; \
        float c10 = (m & 1) ? acc[1][1] : acc[0][1]; \
        float c11 = (m & 1) ? acc[3][1] : acc[2][1]; \
        float c20 = (m & 1) ? acc[1][2] : acc[0][2]; \
        float c21 = (m & 1) ? acc[3][2] : acc[2][2]; \
        float c30 = (m & 1) ? acc[1][3] : acc[0][3]; \
        float c31 = (m & 1) ? acc[3][3] : acc[2][3]; \
        float d0 = (m & 2) ? c01 : c00; \
        float d1 = (m & 2) ? c11 : c10; \
        float d2 = (m & 2) ? c21 : c20; \
        float d3 = (m & 2) ? c31 : c30; \
        float e0 = (m & 4) ? d1 : d0; \
        float e1 = (m & 4) ? d3 : d2; \
        float v  = (m & 8) ? e1 : e0; \
        v += __shfl_xor(v, 16); \
        v += __shfl_xor(v, 32); \
        if (l < 16) { \
            float bs = (m & 2) ? ((m & 1) ? b3 : b2) : ((m & 1) ? b1 : b0); \
            int rr = m & 3; \
            int bb = m >> 2; \
            float hval = tanhf(v + bs); \
            __hip_atomic_store(out + ((size_t)((BGB) + bb) * TT + t) * NN + (n0 + rr), \
                               hval, __ATOMIC_RELAXED, __HIP_MEMORY_SCOPE_AGENT); \
        } \
    } \
    asm volatile("s_waitcnt vmcnt(0)" ::: "memory"); \
    __syncthreads();   /* S2: WG drained (load-bearing, R16) */ \
    if (tid == 0) { \
        __hip_atomic_store(&(GF)[ig], (unsigned)(t + 1), \
                           __ATOMIC_RELAXED, __HIP_MEMORY_SCOPE_AGENT); \
    } \
}

    for (int t = 0; t < TT; ++t) {
        PHASE(gfA, (size_t)0, (size_t)0, bgb)   // chain 2p
        PHASE(gfB, UOFF,      HOFF,      bgb + 8)  // chain 2p+1
        up0 += II; up1 += II; up2 += II; up3 += II;
        hp0 += NN; hp1 += NN; hp2 += NN; hp3 += NN;
    }
#undef UPART
#undef DOT
#undef QSTEP
#undef PHASE
}

extern "C" void kernel_launch(void* const* d_in, const int* in_sizes, int n_in,
                              void* d_out, int out_size, void* d_ws, size_t ws_size,
                              hipStream_t stream) {
    const float* u      = (const float*)d_in[0];
    const float* w_in   = (const float*)d_in[1];
    const float* w      = (const float*)d_in[2];
    const float* w_bias = (const float*)d_in[3];
    float* out          = (float*)d_out;
    unsigned int* flags = (unsigned int*)d_ws;

    // 4 chains x 64 producer flags, zeroed every call (graph-replay safe)
    hipMemsetAsync(flags, 0, 4 * 64 * sizeof(unsigned int), stream);

    // 128 WGs x 512 threads, 96 KB LDS -> 1 WG/CU on 128 of 256 CUs, all
    // co-resident (latency-bound problem: idle CUs cost nothing); flag spin
    // cannot deadlock.
    esn_kernel<<<dim3(NWG), dim3(NTHR), 0, stream>>>(u, w_in, w, w_bias, out, flags);
}

// Round 19
// 12263.352 us; speedup vs baseline: 1.2650x; 1.2650x over previous
//
#include <hip/hip_runtime.h>
#include <math.h>

#define TT 2048
#define II 128
#define NN 1024
#define NWG 256        // 64 i-blocks x 4 j-groups
#define NTHR 512

// R19 = R15 verbatim (best verified: 11.99 ms, absmax 3.9e-3).
// Session summary of what is load-bearing (verified by failures):
//  - drain -> S2 __syncthreads -> tid0 flag store: removing S2 or signaling
//    per-wave reads stale h (R16); atomic-counter variants likewise (R8-R11).
//  - LDS h staging + S1b barrier: cross-wave chunk exchange requires it.
//  - Persistent VGPR set <= ~116: larger sets silently corrupt around
//    inline-asm loads (R3-R5 spill traffic; R8-R11/R14/R17 corruption).
//  - SW swizzle applied to the FULL index (R6/R9 carry bug class).
// Known non-levers: LDS bank conflicts (SQ_LDS_BANK_CONFLICT tracks op count,
// R15 A/B), 2-WG/CU overlap (R13: staging duplicates), chain interleave
// (R18: phases serialize, 15.5 ms). Remaining time = 2048 sequential
// all-to-all exchanges via IC: ~3.8 us warm body + ~2 us sync exposure/step.
#define SW(k) ((k) ^ ((((k) >> 4) & 7) << 2))

__device__ __forceinline__ float dpp_add_xor1(float x) {  // quad_perm [1,0,3,2]
    int y = __builtin_amdgcn_update_dpp(0, __float_as_int(x), 0xB1, 0xF, 0xF, true);
    return x + __int_as_float(y);
}
__device__ __forceinline__ float dpp_add_xor2(float x) {  // quad_perm [2,3,0,1]
    int y = __builtin_amdgcn_update_dpp(0, __float_as_int(x), 0x4E, 0xF, 0xF, true);
    return x + __int_as_float(y);
}
__device__ __forceinline__ float dpp_add_xor8(float x) {  // row_ror:8 (xor8 in row16)
    int y = __builtin_amdgcn_update_dpp(0, __float_as_int(x), 0x128, 0xF, 0xF, true);
    return x + __int_as_float(y);
}

__global__ __launch_bounds__(NTHR)
__attribute__((amdgpu_waves_per_eu(2, 2)))
void esn_kernel(const float* __restrict__ u, const float* __restrict__ w_in,
                const float* __restrict__ w, const float* __restrict__ w_bias,
                float* __restrict__ out, unsigned int* __restrict__ flags)
{
    __shared__ alignas(16) float w_lds[16 * 1024];   // 64 KB, swizzled, static
    __shared__ alignas(16) float h_stage[8 * 1024];  // 32 KB, swizzled, per step

    const int tid = threadIdx.x;
    const int wg  = blockIdx.x;
    const int ig  = wg & 63;
    const int jg  = wg >> 6;
    const int l   = tid & 63;
    const int rt  = (tid >> 6) & 3;
    const int bt  = tid >> 8;            // 0..1
    const int n0  = ig * 16 + rt * 4;
    const int bgb = jg * 8 + bt * 4;

    // ---- stage W tile into LDS once (coalesced global, swizzled LDS) ----
    #pragma unroll
    for (int c = 0; c < 32; ++c) {
        int idx = c * NTHR + tid;        // 0..16383
        int row = idx >> 10;
        int k   = idx & 1023;
        w_lds[row * 1024 + SW(k)] = w[(size_t)(ig * 16 + row) * NN + k];
    }

    // W_in slice (2 floats/row) + bias, in registers
    float2 wir0 = *reinterpret_cast<const float2*>(w_in + (n0 + 0) * II + 2 * l);
    float2 wir1 = *reinterpret_cast<const float2*>(w_in + (n0 + 1) * II + 2 * l);
    float2 wir2 = *reinterpret_cast<const float2*>(w_in + (n0 + 2) * II + 2 * l);
    float2 wir3 = *reinterpret_cast<const float2*>(w_in + (n0 + 3) * II + 2 * l);
    const float b0 = w_bias[n0 + 0];
    const float b1 = w_bias[n0 + 1];
    const float b2 = w_bias[n0 + 2];
    const float b3 = w_bias[n0 + 3];

    // walking pointers
    const float* up0 = u + (size_t)(bgb + 0) * TT * II + 2 * l;
    const float* up1 = u + (size_t)(bgb + 1) * TT * II + 2 * l;
    const float* up2 = u + (size_t)(bgb + 2) * TT * II + 2 * l;
    const float* up3 = u + (size_t)(bgb + 3) * TT * II + 2 * l;

    const float *hp0, *hp1, *hp2, *hp3;
    int hw0, hw1, hw2, hw3;
    {
        int f4, bl, k4;
        f4 = 0 * NTHR + tid; bl = f4 >> 8; k4 = f4 & 255;
        hp0 = out + (size_t)(jg * 8 + bl) * TT * NN + 4 * k4 - NN;
        hw0 = bl * 1024 + SW(4 * k4);
        f4 = 1 * NTHR + tid; bl = f4 >> 8; k4 = f4 & 255;
        hp1 = out + (size_t)(jg * 8 + bl) * TT * NN + 4 * k4 - NN;
        hw1 = bl * 1024 + SW(4 * k4);
        f4 = 2 * NTHR + tid; bl = f4 >> 8; k4 = f4 & 255;
        hp2 = out + (size_t)(jg * 8 + bl) * TT * NN + 4 * k4 - NN;
        hw2 = bl * 1024 + SW(4 * k4);
        f4 = 3 * NTHR + tid; bl = f4 >> 8; k4 = f4 & 255;
        hp3 = out + (size_t)(jg * 8 + bl) * TT * NN + 4 * k4 - NN;
        hw3 = bl * 1024 + SW(4 * k4);
    }

    // per-lane swizzled read offsets: SW applied to the FULL index (R6/R9 lesson)
    const int kl = 16 * l;
    const int o0 = SW(kl + 0);
    const int o1 = SW(kl + 4);
    const int o2 = SW(kl + 8);
    const int o3 = SW(kl + 12);
    const int wb = rt * 4 * 1024;    // row base (k part lives in o0..o3)
    const int hb = bt * 4 * 1024;

    unsigned int* gflags = flags + jg * 64;

    __syncthreads();   // w_lds ready

    float acc[4][4];

#define UPART(bb, uv) \
    acc[0][bb] = wir0.x * uv.x + wir0.y * uv.y; \
    acc[1][bb] = wir1.x * uv.x + wir1.y * uv.y; \
    acc[2][bb] = wir2.x * uv.x + wir2.y * uv.y; \
    acc[3][bb] = wir3.x * uv.x + wir3.y * uv.y;

#define DOT(rr, bb, wv, hv) \
    acc[rr][bb] += wv.x*hv.x + wv.y*hv.y + wv.z*hv.z + wv.w*hv.w;

#define QSTEP(o) { \
    float4 wv0 = *reinterpret_cast<const float4*>(&w_lds[wb + 0*1024 + (o)]); \
    float4 wv1 = *reinterpret_cast<const float4*>(&w_lds[wb + 1*1024 + (o)]); \
    float4 wv2 = *reinterpret_cast<const float4*>(&w_lds[wb + 2*1024 + (o)]); \
    float4 wv3 = *reinterpret_cast<const float4*>(&w_lds[wb + 3*1024 + (o)]); \
    float4 hv0 = *reinterpret_cast<const float4*>(&h_stage[hb + 0*1024 + (o)]); \
    float4 hv1 = *reinterpret_cast<const float4*>(&h_stage[hb + 1*1024 + (o)]); \
    float4 hv2 = *reinterpret_cast<const float4*>(&h_stage[hb + 2*1024 + (o)]); \
    float4 hv3 = *reinterpret_cast<const float4*>(&h_stage[hb + 3*1024 + (o)]); \
    DOT(0,0,wv0,hv0) DOT(1,0,wv1,hv0) DOT(2,0,wv2,hv0) DOT(3,0,wv3,hv0) \
    DOT(0,1,wv0,hv1) DOT(1,1,wv1,hv1) DOT(2,1,wv2,hv1) DOT(3,1,wv3,hv1) \
    DOT(0,2,wv0,hv2) DOT(1,2,wv1,hv2) DOT(2,2,wv2,hv2) DOT(3,2,wv3,hv2) \
    DOT(0,3,wv0,hv3) DOT(1,3,wv1,hv3) DOT(2,3,wv2,hv3) DOT(3,3,wv3,hv3) }

    for (int t = 0; t < TT; ++t) {
        // -- issue u loads (overlap the poll) --
        float2 uv0, uv1, uv2, uv3;
        asm volatile("global_load_dwordx2 %0, %1, off" : "=v"(uv0) : "v"(up0));
        asm volatile("global_load_dwordx2 %0, %1, off" : "=v"(uv1) : "v"(up1));
        asm volatile("global_load_dwordx2 %0, %1, off" : "=v"(uv2) : "v"(up2));
        asm volatile("global_load_dwordx2 %0, %1, off" : "=v"(uv3) : "v"(up3));

        float4 h0, h1, h2, h3;
        if (t > 0) {
            for (;;) {
                unsigned int v = __hip_atomic_load(&gflags[l], __ATOMIC_RELAXED,
                                                   __HIP_MEMORY_SCOPE_AGENT);
                if (__all((int)(v >= (unsigned)t))) break;
                __builtin_amdgcn_s_sleep(1);
            }
            asm volatile("" ::: "memory");
            // h_{t-1} -> regs, IC-coherent (sc1)
            asm volatile("global_load_dwordx4 %0, %1, off sc1" : "=v"(h0) : "v"(hp0));
            asm volatile("global_load_dwordx4 %0, %1, off sc1" : "=v"(h1) : "v"(hp1));
            asm volatile("global_load_dwordx4 %0, %1, off sc1" : "=v"(h2) : "v"(hp2));
            asm volatile("global_load_dwordx4 %0, %1, off sc1" : "=v"(h3) : "v"(hp3));
            asm volatile("s_waitcnt vmcnt(4)" ::: "memory");  // u done, h in flight
            __builtin_amdgcn_sched_barrier(0);
        } else {
            asm volatile("s_waitcnt vmcnt(0)" ::: "memory");
            __builtin_amdgcn_sched_barrier(0);
        }

        // -- W_in . u partial (hides h load latency) --
        UPART(0, uv0) UPART(1, uv1) UPART(2, uv2) UPART(3, uv3)

        if (t > 0) {
            asm volatile("s_waitcnt vmcnt(0)" ::: "memory");  // h regs ready
            __builtin_amdgcn_sched_barrier(0);
            // (S1a removed: S2 of step t-1 orders prior reads vs these writes)
            *reinterpret_cast<float4*>(&h_stage[hw0]) = h0;
            *reinterpret_cast<float4*>(&h_stage[hw1]) = h1;
            *reinterpret_cast<float4*>(&h_stage[hw2]) = h2;
            *reinterpret_cast<float4*>(&h_stage[hw3]) = h3;
        }
        __syncthreads();   // S1b: h_stage visible to all

        // -- main W.h loop: 32 ds_read_b128 + 256 FMA per thread --
        if (t > 0) {
            QSTEP(o0) QSTEP(o1) QSTEP(o2) QSTEP(o3)
        }

        // -- reduce over lane bits 0..3: DPP (VALU) for xor1/2/8, shfl for 4 --
        #pragma unroll
        for (int rr = 0; rr < 4; ++rr)
            #pragma unroll
            for (int bb = 0; bb < 4; ++bb) {
                float a = acc[rr][bb];
                a = dpp_add_xor1(a);
                a = dpp_add_xor2(a);
                a += __shfl_xor(a, 4);
                a = dpp_add_xor8(a);
                acc[rr][bb] = a;
            }

        // -- select tree: lane m (=l&15) takes output (rr = m&3, bb = m>>2) --
        const int m = l & 15;
        float c00 = (m & 1) ? acc[1][0] : acc[0][0];
        float c01 = (m & 1) ? acc[3][0] : acc[2][0];
        float c10 = (m & 1) ? acc[1][1] : acc[0][1];
        float c11 = (m & 1) ? acc[3][1] : acc[2][1];
        float c20 = (m & 1) ? acc[1][2] : acc[0][2];
        float c21 = (m & 1) ? acc[3][2] : acc[2][2];
        float c30 = (m & 1) ? acc[1][3] : acc[0][3];
        float c31 = (m & 1) ? acc[3][3] : acc[2][3];
        float d0 = (m & 2) ? c01 : c00;
        float d1 = (m & 2) ? c11 : c10;
        float d2 = (m & 2) ? c21 : c20;
        float d3 = (m & 2) ? c31 : c30;
        float e0 = (m & 4) ? d1 : d0;
        float e1 = (m & 4) ? d3 : d2;
        float v  = (m & 8) ? e1 : e0;
        // sum the four 16-lane k-subgroups
        v += __shfl_xor(v, 16);
        v += __shfl_xor(v, 32);

        if (l < 16) {
            float bs = (m & 2) ? ((m & 1) ? b3 : b2) : ((m & 1) ? b1 : b0);
            int rr = m & 3;
            int bb = m >> 2;
            float hval = tanhf(v + bs);
            __hip_atomic_store(out + ((size_t)(bgb + bb) * TT + t) * NN + (n0 + rr),
                               hval, __ATOMIC_RELAXED, __HIP_MEMORY_SCOPE_AGENT);
        }

        asm volatile("s_waitcnt vmcnt(0)" ::: "memory");  // h_t stores durable
        __syncthreads();                                  // S2: WG drained
        if (tid == 0) {
            __hip_atomic_store(&gflags[ig], (unsigned)(t + 1),
                               __ATOMIC_RELAXED, __HIP_MEMORY_SCOPE_AGENT);
        }

        up0 += II; up1 += II; up2 += II; up3 += II;
        hp0 += NN; hp1 += NN; hp2 += NN; hp3 += NN;
    }
#undef UPART
#undef DOT
#undef QSTEP
}

extern "C" void kernel_launch(void* const* d_in, const int* in_sizes, int n_in,
                              void* d_out, int out_size, void* d_ws, size_t ws_size,
                              hipStream_t stream) {
    const float* u      = (const float*)d_in[0];
    const float* w_in   = (const float*)d_in[1];
    const float* w      = (const float*)d_in[2];
    const float* w_bias = (const float*)d_in[3];
    float* out          = (float*)d_out;
    unsigned int* flags = (unsigned int*)d_ws;

    hipMemsetAsync(flags, 0, 4 * 64 * sizeof(unsigned int), stream);

    // 256 WGs x 512 threads, 96 KB LDS = exactly 1 WG/CU -> co-residency
    // guaranteed, flag spin cannot deadlock.
    esn_kernel<<<dim3(NWG), dim3(NTHR), 0, stream>>>(u, w_in, w, w_bias, out, flags);
}

// Round 20
// 11433.609 us; speedup vs baseline: 1.3568x; 1.0726x over previous
//
#include <hip/hip_runtime.h>
#include <math.h>

#define TT 2048
#define II 128
#define NN 1024
#define NWG 256        // 64 i-blocks x 4 j-groups
#define NTHR 512

#define SW(k) ((k) ^ ((((k) >> 4) & 7) << 2))

// R20 = R19/R15 base + ONE delta: per-producer fine-grained polling.
// Structural fact: for all 4 staged chunks of a thread, k4 = (c*512+tid)&255
// is IDENTICAL (512 = 0 mod 256) -> each thread stages h from exactly ONE
// producer WG, myp = k4>>2. So each lane polls only gflags[myp] (divergent
// loop) instead of the wave-uniform __all over 64 flags: loads for early
// producers issue while stragglers finish; the WG convoy moves to S1b,
// after load latency is absorbed. Visibility protocol unchanged (flag>=t
// implies that producer's vmcnt-drain + S2 preceded its signal; R16 lesson).
// Register delta ~0; everything else byte-identical to R19.

__device__ __forceinline__ float dpp_add_xor1(float x) {  // quad_perm [1,0,3,2]
    int y = __builtin_amdgcn_update_dpp(0, __float_as_int(x), 0xB1, 0xF, 0xF, true);
    return x + __int_as_float(y);
}
__device__ __forceinline__ float dpp_add_xor2(float x) {  // quad_perm [2,3,0,1]
    int y = __builtin_amdgcn_update_dpp(0, __float_as_int(x), 0x4E, 0xF, 0xF, true);
    return x + __int_as_float(y);
}
__device__ __forceinline__ float dpp_add_xor8(float x) {  // row_ror:8 (xor8 in row16)
    int y = __builtin_amdgcn_update_dpp(0, __float_as_int(x), 0x128, 0xF, 0xF, true);
    return x + __int_as_float(y);
}

__global__ __launch_bounds__(NTHR)
__attribute__((amdgpu_waves_per_eu(2, 2)))
void esn_kernel(const float* __restrict__ u, const float* __restrict__ w_in,
                const float* __restrict__ w, const float* __restrict__ w_bias,
                float* __restrict__ out, unsigned int* __restrict__ flags)
{
    __shared__ alignas(16) float w_lds[16 * 1024];   // 64 KB, swizzled, static
    __shared__ alignas(16) float h_stage[8 * 1024];  // 32 KB, swizzled, per step

    const int tid = threadIdx.x;
    const int wg  = blockIdx.x;
    const int ig  = wg & 63;
    const int jg  = wg >> 6;
    const int l   = tid & 63;
    const int rt  = (tid >> 6) & 3;
    const int bt  = tid >> 8;            // 0..1
    const int n0  = ig * 16 + rt * 4;
    const int bgb = jg * 8 + bt * 4;

    // ---- stage W tile into LDS once (coalesced global, swizzled LDS) ----
    #pragma unroll
    for (int c = 0; c < 32; ++c) {
        int idx = c * NTHR + tid;        // 0..16383
        int row = idx >> 10;
        int k   = idx & 1023;
        w_lds[row * 1024 + SW(k)] = w[(size_t)(ig * 16 + row) * NN + k];
    }

    // W_in slice (2 floats/row) + bias, in registers
    float2 wir0 = *reinterpret_cast<const float2*>(w_in + (n0 + 0) * II + 2 * l);
    float2 wir1 = *reinterpret_cast<const float2*>(w_in + (n0 + 1) * II + 2 * l);
    float2 wir2 = *reinterpret_cast<const float2*>(w_in + (n0 + 2) * II + 2 * l);
    float2 wir3 = *reinterpret_cast<const float2*>(w_in + (n0 + 3) * II + 2 * l);
    const float b0 = w_bias[n0 + 0];
    const float b1 = w_bias[n0 + 1];
    const float b2 = w_bias[n0 + 2];
    const float b3 = w_bias[n0 + 3];

    // walking pointers
    const float* up0 = u + (size_t)(bgb + 0) * TT * II + 2 * l;
    const float* up1 = u + (size_t)(bgb + 1) * TT * II + 2 * l;
    const float* up2 = u + (size_t)(bgb + 2) * TT * II + 2 * l;
    const float* up3 = u + (size_t)(bgb + 3) * TT * II + 2 * l;

    const float *hp0, *hp1, *hp2, *hp3;
    int hw0, hw1, hw2, hw3;
    {
        int f4, bl, k4;
        f4 = 0 * NTHR + tid; bl = f4 >> 8; k4 = f4 & 255;
        hp0 = out + (size_t)(jg * 8 + bl) * TT * NN + 4 * k4 - NN;
        hw0 = bl * 1024 + SW(4 * k4);
        f4 = 1 * NTHR + tid; bl = f4 >> 8; k4 = f4 & 255;
        hp1 = out + (size_t)(jg * 8 + bl) * TT * NN + 4 * k4 - NN;
        hw1 = bl * 1024 + SW(4 * k4);
        f4 = 2 * NTHR + tid; bl = f4 >> 8; k4 = f4 & 255;
        hp2 = out + (size_t)(jg * 8 + bl) * TT * NN + 4 * k4 - NN;
        hw2 = bl * 1024 + SW(4 * k4);
        f4 = 3 * NTHR + tid; bl = f4 >> 8; k4 = f4 & 255;
        hp3 = out + (size_t)(jg * 8 + bl) * TT * NN + 4 * k4 - NN;
        hw3 = bl * 1024 + SW(4 * k4);
    }
    // this thread's single h-producer: all 4 chunks share k4 = tid & 255
    const int myp = (tid & 255) >> 2;

    // per-lane swizzled read offsets: SW applied to the FULL index (R6/R9 lesson)
    const int kl = 16 * l;
    const int o0 = SW(kl + 0);
    const int o1 = SW(kl + 4);
    const int o2 = SW(kl + 8);
    const int o3 = SW(kl + 12);
    const int wb = rt * 4 * 1024;    // row base (k part lives in o0..o3)
    const int hb = bt * 4 * 1024;

    unsigned int* gflags = flags + jg * 64;

    __syncthreads();   // w_lds ready

    float acc[4][4];

#define UPART(bb, uv) \
    acc[0][bb] = wir0.x * uv.x + wir0.y * uv.y; \
    acc[1][bb] = wir1.x * uv.x + wir1.y * uv.y; \
    acc[2][bb] = wir2.x * uv.x + wir2.y * uv.y; \
    acc[3][bb] = wir3.x * uv.x + wir3.y * uv.y;

#define DOT(rr, bb, wv, hv) \
    acc[rr][bb] += wv.x*hv.x + wv.y*hv.y + wv.z*hv.z + wv.w*hv.w;

#define QSTEP(o) { \
    float4 wv0 = *reinterpret_cast<const float4*>(&w_lds[wb + 0*1024 + (o)]); \
    float4 wv1 = *reinterpret_cast<const float4*>(&w_lds[wb + 1*1024 + (o)]); \
    float4 wv2 = *reinterpret_cast<const float4*>(&w_lds[wb + 2*1024 + (o)]); \
    float4 wv3 = *reinterpret_cast<const float4*>(&w_lds[wb + 3*1024 + (o)]); \
    float4 hv0 = *reinterpret_cast<const float4*>(&h_stage[hb + 0*1024 + (o)]); \
    float4 hv1 = *reinterpret_cast<const float4*>(&h_stage[hb + 1*1024 + (o)]); \
    float4 hv2 = *reinterpret_cast<const float4*>(&h_stage[hb + 2*1024 + (o)]); \
    float4 hv3 = *reinterpret_cast<const float4*>(&h_stage[hb + 3*1024 + (o)]); \
    DOT(0,0,wv0,hv0) DOT(1,0,wv1,hv0) DOT(2,0,wv2,hv0) DOT(3,0,wv3,hv0) \
    DOT(0,1,wv0,hv1) DOT(1,1,wv1,hv1) DOT(2,1,wv2,hv1) DOT(3,1,wv3,hv1) \
    DOT(0,2,wv0,hv2) DOT(1,2,wv1,hv2) DOT(2,2,wv2,hv2) DOT(3,2,wv3,hv2) \
    DOT(0,3,wv0,hv3) DOT(1,3,wv1,hv3) DOT(2,3,wv2,hv3) DOT(3,3,wv3,hv3) }

    for (int t = 0; t < TT; ++t) {
        // -- issue u loads (overlap the poll) --
        float2 uv0, uv1, uv2, uv3;
        asm volatile("global_load_dwordx2 %0, %1, off" : "=v"(uv0) : "v"(up0));
        asm volatile("global_load_dwordx2 %0, %1, off" : "=v"(uv1) : "v"(up1));
        asm volatile("global_load_dwordx2 %0, %1, off" : "=v"(uv2) : "v"(up2));
        asm volatile("global_load_dwordx2 %0, %1, off" : "=v"(uv3) : "v"(up3));

        float4 h0, h1, h2, h3;
        if (t > 0) {
            // per-lane poll of this thread's single producer (divergent loop):
            // loads for early producers issue while stragglers finish.
            for (;;) {
                unsigned int v = __hip_atomic_load(&gflags[myp], __ATOMIC_RELAXED,
                                                   __HIP_MEMORY_SCOPE_AGENT);
                if (v >= (unsigned)t) break;
                __builtin_amdgcn_s_sleep(1);
            }
            asm volatile("" ::: "memory");
            // h_{t-1} -> regs, IC-coherent (sc1)
            asm volatile("global_load_dwordx4 %0, %1, off sc1" : "=v"(h0) : "v"(hp0));
            asm volatile("global_load_dwordx4 %0, %1, off sc1" : "=v"(h1) : "v"(hp1));
            asm volatile("global_load_dwordx4 %0, %1, off sc1" : "=v"(h2) : "v"(hp2));
            asm volatile("global_load_dwordx4 %0, %1, off sc1" : "=v"(h3) : "v"(hp3));
            asm volatile("s_waitcnt vmcnt(4)" ::: "memory");  // u done, h in flight
            __builtin_amdgcn_sched_barrier(0);
        } else {
            asm volatile("s_waitcnt vmcnt(0)" ::: "memory");
            __builtin_amdgcn_sched_barrier(0);
        }

        // -- W_in . u partial (hides h load latency) --
        UPART(0, uv0) UPART(1, uv1) UPART(2, uv2) UPART(3, uv3)

        if (t > 0) {
            asm volatile("s_waitcnt vmcnt(0)" ::: "memory");  // h regs ready
            __builtin_amdgcn_sched_barrier(0);
            // (S1a removed: S2 of step t-1 orders prior reads vs these writes)
            *reinterpret_cast<float4*>(&h_stage[hw0]) = h0;
            *reinterpret_cast<float4*>(&h_stage[hw1]) = h1;
            *reinterpret_cast<float4*>(&h_stage[hw2]) = h2;
            *reinterpret_cast<float4*>(&h_stage[hw3]) = h3;
        }
        __syncthreads();   // S1b: h_stage visible to all

        // -- main W.h loop: 32 ds_read_b128 + 256 FMA per thread --
        if (t > 0) {
            QSTEP(o0) QSTEP(o1) QSTEP(o2) QSTEP(o3)
        }

        // -- reduce over lane bits 0..3: DPP (VALU) for xor1/2/8, shfl for 4 --
        #pragma unroll
        for (int rr = 0; rr < 4; ++rr)
            #pragma unroll
            for (int bb = 0; bb < 4; ++bb) {
                float a = acc[rr][bb];
                a = dpp_add_xor1(a);
                a = dpp_add_xor2(a);
                a += __shfl_xor(a, 4);
                a = dpp_add_xor8(a);
                acc[rr][bb] = a;
            }

        // -- select tree: lane m (=l&15) takes output (rr = m&3, bb = m>>2) --
        const int m = l & 15;
        float c00 = (m & 1) ? acc[1][0] : acc[0][0];
        float c01 = (m & 1) ? acc[3][0] : acc[2][0];
        float c10 = (m & 1) ? acc[1][1] : acc[0][1];
        float c11 = (m & 1) ? acc[3][1] : acc[2][1];
        float c20 = (m & 1) ? acc[1][2] : acc[0][2];
        float c21 = (m & 1) ? acc[3][2] : acc[2][2];
        float c30 = (m & 1) ? acc[1][3] : acc[0][3];
        float c31 = (m & 1) ? acc[3][3] : acc[2][3];
        float d0 = (m & 2) ? c01 : c00;
        float d1 = (m & 2) ? c11 : c10;
        float d2 = (m & 2) ? c21 : c20;
        float d3 = (m & 2) ? c31 : c30;
        float e0 = (m & 4) ? d1 : d0;
        float e1 = (m & 4) ? d3 : d2;
        float v  = (m & 8) ? e1 : e0;
        // sum the four 16-lane k-subgroups
        v += __shfl_xor(v, 16);
        v += __shfl_xor(v, 32);

        if (l < 16) {
            float bs = (m & 2) ? ((m & 1) ? b3 : b2) : ((m & 1) ? b1 : b0);
            int rr = m & 3;
            int bb = m >> 2;
            float hval = tanhf(v + bs);
            __hip_atomic_store(out + ((size_t)(bgb + bb) * TT + t) * NN + (n0 + rr),
                               hval, __ATOMIC_RELAXED, __HIP_MEMORY_SCOPE_AGENT);
        }

        asm volatile("s_waitcnt vmcnt(0)" ::: "memory");  // h_t stores durable
        __syncthreads();                                  // S2: WG drained
        if (tid == 0) {
            __hip_atomic_store(&gflags[ig], (unsigned)(t + 1),
                               __ATOMIC_RELAXED, __HIP_MEMORY_SCOPE_AGENT);
        }

        up0 += II; up1 += II; up2 += II; up3 += II;
        hp0 += NN; hp1 += NN; hp2 += NN; hp3 += NN;
    }
#undef UPART
#undef DOT
#undef QSTEP
}

extern "C" void kernel_launch(void* const* d_in, const int* in_sizes, int n_in,
                              void* d_out, int out_size, void* d_ws, size_t ws_size,
                              hipStream_t stream) {
    const float* u      = (const float*)d_in[0];
    const float* w_in   = (const float*)d_in[1];
    const float* w      = (const float*)d_in[2];
    const float* w_bias = (const float*)d_in[3];
    float* out          = (float*)d_out;
    unsigned int* flags = (unsigned int*)d_ws;

    hipMemsetAsync(flags, 0, 4 * 64 * sizeof(unsigned int), stream);

    // 256 WGs x 512 threads, 96 KB LDS = exactly 1 WG/CU -> co-residency
    // guaranteed, flag spin cannot deadlock.
    esn_kernel<<<dim3(NWG), dim3(NTHR), 0, stream>>>(u, w_in, w, w_bias, out, flags);
}

// Round 21
// 11065.143 us; speedup vs baseline: 1.4020x; 1.0333x over previous
//
#include <hip/hip_runtime.h>
#include <math.h>

#define TT 2048
#define II 128
#define NN 1024
#define NWG 256        // 64 i-blocks x 4 j-groups
#define NTHR 512

#define SW(k) ((k) ^ ((((k) >> 4) & 7) << 2))

// R21 = R20 base (11.43 ms) + ONE delta: branch-free fast tanh on the
// producer's critical tail (reduce -> tanh -> store -> drain -> S2 -> signal
// is what every consumer transitively waits on). tanhf is a branchy libm
// call; v_exp_f32 form = clamp(+-9) + exp(2x) + rcp: error ~1e-6 << 3.9e-3
// observed absmax. Zero structural / register delta.
//
// Load-bearing invariants (verified by failure across R3-R18):
//  - drain -> S2 __syncthreads -> tid0 flag store (R16: removing S2 -> stale h)
//  - LDS h staging + S1b barrier
//  - persistent VGPR set <= ~116 (larger corrupts around inline-asm loads)
//  - SW swizzle applied to FULL index (R6/R9 carry-bug class)
//  - per-producer divergent poll (R20: -6.8%, each lane waits only its own
//    producer; k4 = (c*512+tid)&255 identical for all 4 chunks -> 1 producer)

__device__ __forceinline__ float dpp_add_xor1(float x) {  // quad_perm [1,0,3,2]
    int y = __builtin_amdgcn_update_dpp(0, __float_as_int(x), 0xB1, 0xF, 0xF, true);
    return x + __int_as_float(y);
}
__device__ __forceinline__ float dpp_add_xor2(float x) {  // quad_perm [2,3,0,1]
    int y = __builtin_amdgcn_update_dpp(0, __float_as_int(x), 0x4E, 0xF, 0xF, true);
    return x + __int_as_float(y);
}
__device__ __forceinline__ float dpp_add_xor8(float x) {  // row_ror:8 (xor8 in row16)
    int y = __builtin_amdgcn_update_dpp(0, __float_as_int(x), 0x128, 0xF, 0xF, true);
    return x + __int_as_float(y);
}

__global__ __launch_bounds__(NTHR)
__attribute__((amdgpu_waves_per_eu(2, 2)))
void esn_kernel(const float* __restrict__ u, const float* __restrict__ w_in,
                const float* __restrict__ w, const float* __restrict__ w_bias,
                float* __restrict__ out, unsigned int* __restrict__ flags)
{
    __shared__ alignas(16) float w_lds[16 * 1024];   // 64 KB, swizzled, static
    __shared__ alignas(16) float h_stage[8 * 1024];  // 32 KB, swizzled, per step

    const int tid = threadIdx.x;
    const int wg  = blockIdx.x;
    const int ig  = wg & 63;
    const int jg  = wg >> 6;
    const int l   = tid & 63;
    const int rt  = (tid >> 6) & 3;
    const int bt  = tid >> 8;            // 0..1
    const int n0  = ig * 16 + rt * 4;
    const int bgb = jg * 8 + bt * 4;

    // ---- stage W tile into LDS once (coalesced global, swizzled LDS) ----
    #pragma unroll
    for (int c = 0; c < 32; ++c) {
        int idx = c * NTHR + tid;        // 0..16383
        int row = idx >> 10;
        int k   = idx & 1023;
        w_lds[row * 1024 + SW(k)] = w[(size_t)(ig * 16 + row) * NN + k];
    }

    // W_in slice (2 floats/row) + bias, in registers
    float2 wir0 = *reinterpret_cast<const float2*>(w_in + (n0 + 0) * II + 2 * l);
    float2 wir1 = *reinterpret_cast<const float2*>(w_in + (n0 + 1) * II + 2 * l);
    float2 wir2 = *reinterpret_cast<const float2*>(w_in + (n0 + 2) * II + 2 * l);
    float2 wir3 = *reinterpret_cast<const float2*>(w_in + (n0 + 3) * II + 2 * l);
    const float b0 = w_bias[n0 + 0];
    const float b1 = w_bias[n0 + 1];
    const float b2 = w_bias[n0 + 2];
    const float b3 = w_bias[n0 + 3];

    // walking pointers
    const float* up0 = u + (size_t)(bgb + 0) * TT * II + 2 * l;
    const float* up1 = u + (size_t)(bgb + 1) * TT * II + 2 * l;
    const float* up2 = u + (size_t)(bgb + 2) * TT * II + 2 * l;
    const float* up3 = u + (size_t)(bgb + 3) * TT * II + 2 * l;

    const float *hp0, *hp1, *hp2, *hp3;
    int hw0, hw1, hw2, hw3;
    {
        int f4, bl, k4;
        f4 = 0 * NTHR + tid; bl = f4 >> 8; k4 = f4 & 255;
        hp0 = out + (size_t)(jg * 8 + bl) * TT * NN + 4 * k4 - NN;
        hw0 = bl * 1024 + SW(4 * k4);
        f4 = 1 * NTHR + tid; bl = f4 >> 8; k4 = f4 & 255;
        hp1 = out + (size_t)(jg * 8 + bl) * TT * NN + 4 * k4 - NN;
        hw1 = bl * 1024 + SW(4 * k4);
        f4 = 2 * NTHR + tid; bl = f4 >> 8; k4 = f4 & 255;
        hp2 = out + (size_t)(jg * 8 + bl) * TT * NN + 4 * k4 - NN;
        hw2 = bl * 1024 + SW(4 * k4);
        f4 = 3 * NTHR + tid; bl = f4 >> 8; k4 = f4 & 255;
        hp3 = out + (size_t)(jg * 8 + bl) * TT * NN + 4 * k4 - NN;
        hw3 = bl * 1024 + SW(4 * k4);
    }
    // this thread's single h-producer: all 4 chunks share k4 = tid & 255
    const int myp = (tid & 255) >> 2;

    // per-lane swizzled read offsets: SW applied to the FULL index (R6/R9 lesson)
    const int kl = 16 * l;
    const int o0 = SW(kl + 0);
    const int o1 = SW(kl + 4);
    const int o2 = SW(kl + 8);
    const int o3 = SW(kl + 12);
    const int wb = rt * 4 * 1024;    // row base (k part lives in o0..o3)
    const int hb = bt * 4 * 1024;

    unsigned int* gflags = flags + jg * 64;

    __syncthreads();   // w_lds ready

    float acc[4][4];

#define UPART(bb, uv) \
    acc[0][bb] = wir0.x * uv.x + wir0.y * uv.y; \
    acc[1][bb] = wir1.x * uv.x + wir1.y * uv.y; \
    acc[2][bb] = wir2.x * uv.x + wir2.y * uv.y; \
    acc[3][bb] = wir3.x * uv.x + wir3.y * uv.y;

#define DOT(rr, bb, wv, hv) \
    acc[rr][bb] += wv.x*hv.x + wv.y*hv.y + wv.z*hv.z + wv.w*hv.w;

#define QSTEP(o) { \
    float4 wv0 = *reinterpret_cast<const float4*>(&w_lds[wb + 0*1024 + (o)]); \
    float4 wv1 = *reinterpret_cast<const float4*>(&w_lds[wb + 1*1024 + (o)]); \
    float4 wv2 = *reinterpret_cast<const float4*>(&w_lds[wb + 2*1024 + (o)]); \
    float4 wv3 = *reinterpret_cast<const float4*>(&w_lds[wb + 3*1024 + (o)]); \
    float4 hv0 = *reinterpret_cast<const float4*>(&h_stage[hb + 0*1024 + (o)]); \
    float4 hv1 = *reinterpret_cast<const float4*>(&h_stage[hb + 1*1024 + (o)]); \
    float4 hv2 = *reinterpret_cast<const float4*>(&h_stage[hb + 2*1024 + (o)]); \
    float4 hv3 = *reinterpret_cast<const float4*>(&h_stage[hb + 3*1024 + (o)]); \
    DOT(0,0,wv0,hv0) DOT(1,0,wv1,hv0) DOT(2,0,wv2,hv0) DOT(3,0,wv3,hv0) \
    DOT(0,1,wv0,hv1) DOT(1,1,wv1,hv1) DOT(2,1,wv2,hv1) DOT(3,1,wv3,hv1) \
    DOT(0,2,wv0,hv2) DOT(1,2,wv1,hv2) DOT(2,2,wv2,hv2) DOT(3,2,wv3,hv2) \
    DOT(0,3,wv0,hv3) DOT(1,3,wv1,hv3) DOT(2,3,wv2,hv3) DOT(3,3,wv3,hv3) }

    for (int t = 0; t < TT; ++t) {
        // -- issue u loads (overlap the poll) --
        float2 uv0, uv1, uv2, uv3;
        asm volatile("global_load_dwordx2 %0, %1, off" : "=v"(uv0) : "v"(up0));
        asm volatile("global_load_dwordx2 %0, %1, off" : "=v"(uv1) : "v"(up1));
        asm volatile("global_load_dwordx2 %0, %1, off" : "=v"(uv2) : "v"(up2));
        asm volatile("global_load_dwordx2 %0, %1, off" : "=v"(uv3) : "v"(up3));

        float4 h0, h1, h2, h3;
        if (t > 0) {
            // per-lane poll of this thread's single producer (divergent loop)
            for (;;) {
                unsigned int v = __hip_atomic_load(&gflags[myp], __ATOMIC_RELAXED,
                                                   __HIP_MEMORY_SCOPE_AGENT);
                if (v >= (unsigned)t) break;
                __builtin_amdgcn_s_sleep(1);
            }
            asm volatile("" ::: "memory");
            // h_{t-1} -> regs, IC-coherent (sc1)
            asm volatile("global_load_dwordx4 %0, %1, off sc1" : "=v"(h0) : "v"(hp0));
            asm volatile("global_load_dwordx4 %0, %1, off sc1" : "=v"(h1) : "v"(hp1));
            asm volatile("global_load_dwordx4 %0, %1, off sc1" : "=v"(h2) : "v"(hp2));
            asm volatile("global_load_dwordx4 %0, %1, off sc1" : "=v"(h3) : "v"(hp3));
            asm volatile("s_waitcnt vmcnt(4)" ::: "memory");  // u done, h in flight
            __builtin_amdgcn_sched_barrier(0);
        } else {
            asm volatile("s_waitcnt vmcnt(0)" ::: "memory");
            __builtin_amdgcn_sched_barrier(0);
        }

        // -- W_in . u partial (hides h load latency) --
        UPART(0, uv0) UPART(1, uv1) UPART(2, uv2) UPART(3, uv3)

        if (t > 0) {
            asm volatile("s_waitcnt vmcnt(0)" ::: "memory");  // h regs ready
            __builtin_amdgcn_sched_barrier(0);
            *reinterpret_cast<float4*>(&h_stage[hw0]) = h0;
            *reinterpret_cast<float4*>(&h_stage[hw1]) = h1;
            *reinterpret_cast<float4*>(&h_stage[hw2]) = h2;
            *reinterpret_cast<float4*>(&h_stage[hw3]) = h3;
        }
        __syncthreads();   // S1b: h_stage visible to all

        // -- main W.h loop: 32 ds_read_b128 + 256 FMA per thread --
        if (t > 0) {
            QSTEP(o0) QSTEP(o1) QSTEP(o2) QSTEP(o3)
        }

        // -- reduce over lane bits 0..3: DPP (VALU) for xor1/2/8, shfl for 4 --
        #pragma unroll
        for (int rr = 0; rr < 4; ++rr)
            #pragma unroll
            for (int bb = 0; bb < 4; ++bb) {
                float a = acc[rr][bb];
                a = dpp_add_xor1(a);
                a = dpp_add_xor2(a);
                a += __shfl_xor(a, 4);
                a = dpp_add_xor8(a);
                acc[rr][bb] = a;
            }

        // -- select tree: lane m (=l&15) takes output (rr = m&3, bb = m>>2) --
        const int m = l & 15;
        float c00 = (m & 1) ? acc[1][0] : acc[0][0];
        float c01 = (m & 1) ? acc[3][0] : acc[2][0];
        float c10 = (m & 1) ? acc[1][1] : acc[0][1];
        float c11 = (m & 1) ? acc[3][1] : acc[2][1];
        float c20 = (m & 1) ? acc[1][2] : acc[0][2];
        float c21 = (m & 1) ? acc[3][2] : acc[2][2];
        float c30 = (m & 1) ? acc[1][3] : acc[0][3];
        float c31 = (m & 1) ? acc[3][3] : acc[2][3];
        float d0 = (m & 2) ? c01 : c00;
        float d1 = (m & 2) ? c11 : c10;
        float d2 = (m & 2) ? c21 : c20;
        float d3 = (m & 2) ? c31 : c30;
        float e0 = (m & 4) ? d1 : d0;
        float e1 = (m & 4) ? d3 : d2;
        float v  = (m & 8) ? e1 : e0;
        // sum the four 16-lane k-subgroups
        v += __shfl_xor(v, 16);
        v += __shfl_xor(v, 32);

        if (l < 16) {
            float bs = (m & 2) ? ((m & 1) ? b3 : b2) : ((m & 1) ? b1 : b0);
            int rr = m & 3;
            int bb = m >> 2;
            // branch-free fast tanh: tanh(x) = 1 - 2/(e^{2x}+1); |err| ~1e-6
            float x  = v + bs;
            x = fminf(fmaxf(x, -9.f), 9.f);
            float ex = __expf(2.f * x);
            float hval = 1.f - 2.f / (ex + 1.f);
            __hip_atomic_store(out + ((size_t)(bgb + bb) * TT + t) * NN + (n0 + rr),
                               hval, __ATOMIC_RELAXED, __HIP_MEMORY_SCOPE_AGENT);
        }

        asm volatile("s_waitcnt vmcnt(0)" ::: "memory");  // h_t stores durable
        __syncthreads();                                  // S2: WG drained
        if (tid == 0) {
            __hip_atomic_store(&gflags[ig], (unsigned)(t + 1),
                               __ATOMIC_RELAXED, __HIP_MEMORY_SCOPE_AGENT);
        }

        up0 += II; up1 += II; up2 += II; up3 += II;
        hp0 += NN; hp1 += NN; hp2 += NN; hp3 += NN;
    }
#undef UPART
#undef DOT
#undef QSTEP
}

extern "C" void kernel_launch(void* const* d_in, const int* in_sizes, int n_in,
                              void* d_out, int out_size, void* d_ws, size_t ws_size,
                              hipStream_t stream) {
    const float* u      = (const float*)d_in[0];
    const float* w_in   = (const float*)d_in[1];
    const float* w      = (const float*)d_in[2];
    const float* w_bias = (const float*)d_in[3];
    float* out          = (float*)d_out;
    unsigned int* flags = (unsigned int*)d_ws;

    hipMemsetAsync(flags, 0, 4 * 64 * sizeof(unsigned int), stream);

    // 256 WGs x 512 threads, 96 KB LDS = exactly 1 WG/CU -> co-residency
    // guaranteed, flag spin cannot deadlock.
    esn_kernel<<<dim3(NWG), dim3(NTHR), 0, stream>>>(u, w_in, w, w_bias, out, flags);
}

// Round 23
// 8712.307 us; speedup vs baseline: 1.7806x; 1.2701x over previous
//
#include <hip/hip_runtime.h>
#include <math.h>

#define TT 2048
#define II 128
#define NN 1024
#define NWG 256        // 64 i-blocks x 4 j-groups
#define NTHR 512

#define SW(k) ((k) ^ ((((k) >> 4) & 7) << 2))

// R23 = R22 (flag-line padding, -20%) + the ordering fix its failure exposed.
// R22 post-mortem: vmcnt(0)-retire of a plain sc1 store does NOT mean the
// store is visible at the IC (R16 first showed this); padded flag lines made
// the signal fast enough to outrun the h stores -> intermittent stale-h reads
// across graph replays (first check passed, post-timing diverged).
// FIX: produce h via __hip_atomic_exchange -- atomics are PERFORMED AT the
// IC coherence point, and the returned-value ack means vmcnt(0) retire ==
// IC-visible. Result is consumed by an asm sink so the compiler cannot
// legalize the unused-result swap back into a plain store.
// Order: h swaps @IC -> vmcnt(0) -> S2 -> flag store -> consumer poll ->
// sc1 loads hit IC -> fresh h, independent of signal propagation speed.
//
// Other load-bearing invariants (verified by failure across R3-R18):
//  - drain -> S2 __syncthreads -> tid0 flag store
//  - LDS h staging + S1b barrier; persistent VGPRs <= ~116
//  - SW swizzle on the FULL index; per-producer divergent poll (R20)
//  - fast tanh on the signal path (R21)

#define FSTRIDE 32     // dwords between flags: 128 B = private IC line

__device__ __forceinline__ float dpp_add_xor1(float x) {  // quad_perm [1,0,3,2]
    int y = __builtin_amdgcn_update_dpp(0, __float_as_int(x), 0xB1, 0xF, 0xF, true);
    return x + __int_as_float(y);
}
__device__ __forceinline__ float dpp_add_xor2(float x) {  // quad_perm [2,3,0,1]
    int y = __builtin_amdgcn_update_dpp(0, __float_as_int(x), 0x4E, 0xF, 0xF, true);
    return x + __int_as_float(y);
}
__device__ __forceinline__ float dpp_add_xor8(float x) {  // row_ror:8 (xor8 in row16)
    int y = __builtin_amdgcn_update_dpp(0, __float_as_int(x), 0x128, 0xF, 0xF, true);
    return x + __int_as_float(y);
}

__global__ __launch_bounds__(NTHR)
__attribute__((amdgpu_waves_per_eu(2, 2)))
void esn_kernel(const float* __restrict__ u, const float* __restrict__ w_in,
                const float* __restrict__ w, const float* __restrict__ w_bias,
                float* __restrict__ out, unsigned int* __restrict__ flags)
{
    __shared__ alignas(16) float w_lds[16 * 1024];   // 64 KB, swizzled, static
    __shared__ alignas(16) float h_stage[8 * 1024];  // 32 KB, swizzled, per step

    const int tid = threadIdx.x;
    const int wg  = blockIdx.x;
    const int ig  = wg & 63;
    const int jg  = wg >> 6;
    const int l   = tid & 63;
    const int rt  = (tid >> 6) & 3;
    const int bt  = tid >> 8;            // 0..1
    const int n0  = ig * 16 + rt * 4;
    const int bgb = jg * 8 + bt * 4;

    // ---- stage W tile into LDS once (coalesced global, swizzled LDS) ----
    #pragma unroll
    for (int c = 0; c < 32; ++c) {
        int idx = c * NTHR + tid;        // 0..16383
        int row = idx >> 10;
        int k   = idx & 1023;
        w_lds[row * 1024 + SW(k)] = w[(size_t)(ig * 16 + row) * NN + k];
    }

    // W_in slice (2 floats/row) + bias, in registers
    float2 wir0 = *reinterpret_cast<const float2*>(w_in + (n0 + 0) * II + 2 * l);
    float2 wir1 = *reinterpret_cast<const float2*>(w_in + (n0 + 1) * II + 2 * l);
    float2 wir2 = *reinterpret_cast<const float2*>(w_in + (n0 + 2) * II + 2 * l);
    float2 wir3 = *reinterpret_cast<const float2*>(w_in + (n0 + 3) * II + 2 * l);
    const float b0 = w_bias[n0 + 0];
    const float b1 = w_bias[n0 + 1];
    const float b2 = w_bias[n0 + 2];
    const float b3 = w_bias[n0 + 3];

    // walking pointers
    const float* up0 = u + (size_t)(bgb + 0) * TT * II + 2 * l;
    const float* up1 = u + (size_t)(bgb + 1) * TT * II + 2 * l;
    const float* up2 = u + (size_t)(bgb + 2) * TT * II + 2 * l;
    const float* up3 = u + (size_t)(bgb + 3) * TT * II + 2 * l;

    const float *hp0, *hp1, *hp2, *hp3;
    int hw0, hw1, hw2, hw3;
    {
        int f4, bl, k4;
        f4 = 0 * NTHR + tid; bl = f4 >> 8; k4 = f4 & 255;
        hp0 = out + (size_t)(jg * 8 + bl) * TT * NN + 4 * k4 - NN;
        hw0 = bl * 1024 + SW(4 * k4);
        f4 = 1 * NTHR + tid; bl = f4 >> 8; k4 = f4 & 255;
        hp1 = out + (size_t)(jg * 8 + bl) * TT * NN + 4 * k4 - NN;
        hw1 = bl * 1024 + SW(4 * k4);
        f4 = 2 * NTHR + tid; bl = f4 >> 8; k4 = f4 & 255;
        hp2 = out + (size_t)(jg * 8 + bl) * TT * NN + 4 * k4 - NN;
        hw2 = bl * 1024 + SW(4 * k4);
        f4 = 3 * NTHR + tid; bl = f4 >> 8; k4 = f4 & 255;
        hp3 = out + (size_t)(jg * 8 + bl) * TT * NN + 4 * k4 - NN;
        hw3 = bl * 1024 + SW(4 * k4);
    }
    // this thread's single h-producer: all 4 chunks share k4 = tid & 255
    const int myp = (tid & 255) >> 2;

    // per-lane swizzled read offsets: SW applied to the FULL index (R6/R9 lesson)
    const int kl = 16 * l;
    const int o0 = SW(kl + 0);
    const int o1 = SW(kl + 4);
    const int o2 = SW(kl + 8);
    const int o3 = SW(kl + 12);
    const int wb = rt * 4 * 1024;    // row base (k part lives in o0..o3)
    const int hb = bt * 4 * 1024;

    // padded flag addressing: one 128 B line per flag
    unsigned int* gflags = flags + (size_t)jg * 64 * FSTRIDE;
    unsigned int* mypf   = gflags + (size_t)myp * FSTRIDE;
    unsigned int* mysig  = gflags + (size_t)ig * FSTRIDE;

    __syncthreads();   // w_lds ready

    float acc[4][4];

#define UPART(bb, uv) \
    acc[0][bb] = wir0.x * uv.x + wir0.y * uv.y; \
    acc[1][bb] = wir1.x * uv.x + wir1.y * uv.y; \
    acc[2][bb] = wir2.x * uv.x + wir2.y * uv.y; \
    acc[3][bb] = wir3.x * uv.x + wir3.y * uv.y;

#define DOT(rr, bb, wv, hv) \
    acc[rr][bb] += wv.x*hv.x + wv.y*hv.y + wv.z*hv.z + wv.w*hv.w;

#define QSTEP(o) { \
    float4 wv0 = *reinterpret_cast<const float4*>(&w_lds[wb + 0*1024 + (o)]); \
    float4 wv1 = *reinterpret_cast<const float4*>(&w_lds[wb + 1*1024 + (o)]); \
    float4 wv2 = *reinterpret_cast<const float4*>(&w_lds[wb + 2*1024 + (o)]); \
    float4 wv3 = *reinterpret_cast<const float4*>(&w_lds[wb + 3*1024 + (o)]); \
    float4 hv0 = *reinterpret_cast<const float4*>(&h_stage[hb + 0*1024 + (o)]); \
    float4 hv1 = *reinterpret_cast<const float4*>(&h_stage[hb + 1*1024 + (o)]); \
    float4 hv2 = *reinterpret_cast<const float4*>(&h_stage[hb + 2*1024 + (o)]); \
    float4 hv3 = *reinterpret_cast<const float4*>(&h_stage[hb + 3*1024 + (o)]); \
    DOT(0,0,wv0,hv0) DOT(1,0,wv1,hv0) DOT(2,0,wv2,hv0) DOT(3,0,wv3,hv0) \
    DOT(0,1,wv0,hv1) DOT(1,1,wv1,hv1) DOT(2,1,wv2,hv1) DOT(3,1,wv3,hv1) \
    DOT(0,2,wv0,hv2) DOT(1,2,wv1,hv2) DOT(2,2,wv2,hv2) DOT(3,2,wv3,hv2) \
    DOT(0,3,wv0,hv3) DOT(1,3,wv1,hv3) DOT(2,3,wv2,hv3) DOT(3,3,wv3,hv3) }

    for (int t = 0; t < TT; ++t) {
        // -- issue u loads (overlap the poll) --
        float2 uv0, uv1, uv2, uv3;
        asm volatile("global_load_dwordx2 %0, %1, off" : "=v"(uv0) : "v"(up0));
        asm volatile("global_load_dwordx2 %0, %1, off" : "=v"(uv1) : "v"(up1));
        asm volatile("global_load_dwordx2 %0, %1, off" : "=v"(uv2) : "v"(up2));
        asm volatile("global_load_dwordx2 %0, %1, off" : "=v"(uv3) : "v"(up3));

        float4 h0, h1, h2, h3;
        if (t > 0) {
            // per-lane poll of this thread's single producer (divergent loop)
            for (;;) {
                unsigned int v = __hip_atomic_load(mypf, __ATOMIC_RELAXED,
                                                   __HIP_MEMORY_SCOPE_AGENT);
                if (v >= (unsigned)t) break;
                __builtin_amdgcn_s_sleep(1);
            }
            asm volatile("" ::: "memory");
            // h_{t-1} -> regs, IC-coherent (sc1)
            asm volatile("global_load_dwordx4 %0, %1, off sc1" : "=v"(h0) : "v"(hp0));
            asm volatile("global_load_dwordx4 %0, %1, off sc1" : "=v"(h1) : "v"(hp1));
            asm volatile("global_load_dwordx4 %0, %1, off sc1" : "=v"(h2) : "v"(hp2));
            asm volatile("global_load_dwordx4 %0, %1, off sc1" : "=v"(h3) : "v"(hp3));
            asm volatile("s_waitcnt vmcnt(4)" ::: "memory");  // u done, h in flight
            __builtin_amdgcn_sched_barrier(0);
        } else {
            asm volatile("s_waitcnt vmcnt(0)" ::: "memory");
            __builtin_amdgcn_sched_barrier(0);
        }

        // -- W_in . u partial (hides h load latency) --
        UPART(0, uv0) UPART(1, uv1) UPART(2, uv2) UPART(3, uv3)

        if (t > 0) {
            asm volatile("s_waitcnt vmcnt(0)" ::: "memory");  // h regs ready
            __builtin_amdgcn_sched_barrier(0);
            *reinterpret_cast<float4*>(&h_stage[hw0]) = h0;
            *reinterpret_cast<float4*>(&h_stage[hw1]) = h1;
            *reinterpret_cast<float4*>(&h_stage[hw2]) = h2;
            *reinterpret_cast<float4*>(&h_stage[hw3]) = h3;
        }
        __syncthreads();   // S1b: h_stage visible to all

        // -- main W.h loop: 32 ds_read_b128 + 256 FMA per thread --
        if (t > 0) {
            QSTEP(o0) QSTEP(o1) QSTEP(o2) QSTEP(o3)
        }

        // -- reduce over lane bits 0..3: DPP (VALU) for xor1/2/8, shfl for 4 --
        #pragma unroll
        for (int rr = 0; rr < 4; ++rr)
            #pragma unroll
            for (int bb = 0; bb < 4; ++bb) {
                float a = acc[rr][bb];
                a = dpp_add_xor1(a);
                a = dpp_add_xor2(a);
                a += __shfl_xor(a, 4);
                a = dpp_add_xor8(a);
                acc[rr][bb] = a;
            }

        // -- select tree: lane m (=l&15) takes output (rr = m&3, bb = m>>2) --
        const int m = l & 15;
        float c00 = (m & 1) ? acc[1][0] : acc[0][0];
        float c01 = (m & 1) ? acc[3][0] : acc[2][0];
        float c10 = (m & 1) ? acc[1][1] : acc[0][1];
        float c11 = (m & 1) ? acc[3][1] : acc[2][1];
        float c20 = (m & 1) ? acc[1][2] : acc[0][2];
        float c21 = (m & 1) ? acc[3][2] : acc[2][2];
        float c30 = (m & 1) ? acc[1][3] : acc[0][3];
        float c31 = (m & 1) ? acc[3][3] : acc[2][3];
        float d0 = (m & 2) ? c01 : c00;
        float d1 = (m & 2) ? c11 : c10;
        float d2 = (m & 2) ? c21 : c20;
        float d3 = (m & 2) ? c31 : c30;
        float e0 = (m & 4) ? d1 : d0;
        float e1 = (m & 4) ? d3 : d2;
        float v  = (m & 8) ? e1 : e0;
        // sum the four 16-lane k-subgroups
        v += __shfl_xor(v, 16);
        v += __shfl_xor(v, 32);

        if (l < 16) {
            float bs = (m & 2) ? ((m & 1) ? b3 : b2) : ((m & 1) ? b1 : b0);
            int rr = m & 3;
            int bb = m >> 2;
            // branch-free fast tanh: tanh(x) = 1 - 2/(e^{2x}+1); |err| ~1e-6
            float x  = v + bs;
            x = fminf(fmaxf(x, -9.f), 9.f);
            float ex = __expf(2.f * x);
            float hval = 1.f - 2.f / (ex + 1.f);
            // h output as atomic EXCHANGE: performed AT the IC, so the
            // vmcnt(0) drain below == IC-visible (closes the R22 race).
            float old = __hip_atomic_exchange(
                out + ((size_t)(bgb + bb) * TT + t) * NN + (n0 + rr),
                hval, __ATOMIC_RELAXED, __HIP_MEMORY_SCOPE_AGENT);
            asm volatile("" :: "v"(old));   // keep the RMW form (no store demotion)
        }

        asm volatile("s_waitcnt vmcnt(0)" ::: "memory");  // h_t performed at IC
        __syncthreads();                                  // S2: WG drained
        if (tid == 0) {
            __hip_atomic_store(mysig, (unsigned)(t + 1),
                               __ATOMIC_RELAXED, __HIP_MEMORY_SCOPE_AGENT);
        }

        up0 += II; up1 += II; up2 += II; up3 += II;
        hp0 += NN; hp1 += NN; hp2 += NN; hp3 += NN;
    }
#undef UPART
#undef DOT
#undef QSTEP
}

extern "C" void kernel_launch(void* const* d_in, const int* in_sizes, int n_in,
                              void* d_out, int out_size, void* d_ws, size_t ws_size,
                              hipStream_t stream) {
    const float* u      = (const float*)d_in[0];
    const float* w_in   = (const float*)d_in[1];
    const float* w      = (const float*)d_in[2];
    const float* w_bias = (const float*)d_in[3];
    float* out          = (float*)d_out;
    unsigned int* flags = (unsigned int*)d_ws;

    // 4 j-groups x 64 flags x 32-dword (128 B) padding = 32 KB, zeroed per call
    hipMemsetAsync(flags, 0, 4 * 64 * FSTRIDE * sizeof(unsigned int), stream);

    // 256 WGs x 512 threads, 96 KB LDS = exactly 1 WG/CU -> co-residency
    // guaranteed, flag spin cannot deadlock.
    esn_kernel<<<dim3(NWG), dim3(NTHR), 0, stream>>>(u, w_in, w, w_bias, out, flags);
}

// Round 24
// 8656.375 us; speedup vs baseline: 1.7921x; 1.0065x over previous
//
#include <hip/hip_runtime.h>
#include <math.h>

#define TT 2048
#define II 128
#define NN 1024
#define NWG 256        // 64 i-blocks x 4 j-groups
#define NTHR 512

#define SW(k) ((k) ^ ((((k) >> 4) & 7) << 2))

// R24 = R23 base (8.71 ms, race-free) + ONE delta: incremental per-lane
// h-load issue inside the poll loop. R20's divergent poll reconverges BEFORE
// the loads -> a wave issues all 4 sc1 loads only after its slowest-of-16
// producers signals. Now each lane issues its loads (exec-masked volatile
// asm) the iteration its own producer flags ready: early lanes' ~0.25us IC
// latency overlaps the straggler wait. vmcnt: variable issue counts ->
// single vmcnt(0) before UPART (replaces the vmcnt(4)/vmcnt(0) pair).
//
// Load-bearing invariants (verified by failure):
//  - h produced via atomic EXCHANGE (R23: IC-performed at vmcnt retire;
//    closes the R22 store-visibility race) + asm sink on the result
//  - drain -> S2 __syncthreads -> tid0 flag store (R16)
//  - flag-line padding FSTRIDE=32 (R22: -20%)
//  - LDS h staging + S1b; persistent VGPRs <= ~116; SW on FULL index
//  - fast tanh on the signal path (R21)

#define FSTRIDE 32     // dwords between flags: 128 B = private IC line

__device__ __forceinline__ float dpp_add_xor1(float x) {  // quad_perm [1,0,3,2]
    int y = __builtin_amdgcn_update_dpp(0, __float_as_int(x), 0xB1, 0xF, 0xF, true);
    return x + __int_as_float(y);
}
__device__ __forceinline__ float dpp_add_xor2(float x) {  // quad_perm [2,3,0,1]
    int y = __builtin_amdgcn_update_dpp(0, __float_as_int(x), 0x4E, 0xF, 0xF, true);
    return x + __int_as_float(y);
}
__device__ __forceinline__ float dpp_add_xor8(float x) {  // row_ror:8 (xor8 in row16)
    int y = __builtin_amdgcn_update_dpp(0, __float_as_int(x), 0x128, 0xF, 0xF, true);
    return x + __int_as_float(y);
}

__global__ __launch_bounds__(NTHR)
__attribute__((amdgpu_waves_per_eu(2, 2)))
void esn_kernel(const float* __restrict__ u, const float* __restrict__ w_in,
                const float* __restrict__ w, const float* __restrict__ w_bias,
                float* __restrict__ out, unsigned int* __restrict__ flags)
{
    __shared__ alignas(16) float w_lds[16 * 1024];   // 64 KB, swizzled, static
    __shared__ alignas(16) float h_stage[8 * 1024];  // 32 KB, swizzled, per step

    const int tid = threadIdx.x;
    const int wg  = blockIdx.x;
    const int ig  = wg & 63;
    const int jg  = wg >> 6;
    const int l   = tid & 63;
    const int rt  = (tid >> 6) & 3;
    const int bt  = tid >> 8;            // 0..1
    const int n0  = ig * 16 + rt * 4;
    const int bgb = jg * 8 + bt * 4;

    // ---- stage W tile into LDS once (coalesced global, swizzled LDS) ----
    #pragma unroll
    for (int c = 0; c < 32; ++c) {
        int idx = c * NTHR + tid;        // 0..16383
        int row = idx >> 10;
        int k   = idx & 1023;
        w_lds[row * 1024 + SW(k)] = w[(size_t)(ig * 16 + row) * NN + k];
    }

    // W_in slice (2 floats/row) + bias, in registers
    float2 wir0 = *reinterpret_cast<const float2*>(w_in + (n0 + 0) * II + 2 * l);
    float2 wir1 = *reinterpret_cast<const float2*>(w_in + (n0 + 1) * II + 2 * l);
    float2 wir2 = *reinterpret_cast<const float2*>(w_in + (n0 + 2) * II + 2 * l);
    float2 wir3 = *reinterpret_cast<const float2*>(w_in + (n0 + 3) * II + 2 * l);
    const float b0 = w_bias[n0 + 0];
    const float b1 = w_bias[n0 + 1];
    const float b2 = w_bias[n0 + 2];
    const float b3 = w_bias[n0 + 3];

    // walking pointers
    const float* up0 = u + (size_t)(bgb + 0) * TT * II + 2 * l;
    const float* up1 = u + (size_t)(bgb + 1) * TT * II + 2 * l;
    const float* up2 = u + (size_t)(bgb + 2) * TT * II + 2 * l;
    const float* up3 = u + (size_t)(bgb + 3) * TT * II + 2 * l;

    const float *hp0, *hp1, *hp2, *hp3;
    int hw0, hw1, hw2, hw3;
    {
        int f4, bl, k4;
        f4 = 0 * NTHR + tid; bl = f4 >> 8; k4 = f4 & 255;
        hp0 = out + (size_t)(jg * 8 + bl) * TT * NN + 4 * k4 - NN;
        hw0 = bl * 1024 + SW(4 * k4);
        f4 = 1 * NTHR + tid; bl = f4 >> 8; k4 = f4 & 255;
        hp1 = out + (size_t)(jg * 8 + bl) * TT * NN + 4 * k4 - NN;
        hw1 = bl * 1024 + SW(4 * k4);
        f4 = 2 * NTHR + tid; bl = f4 >> 8; k4 = f4 & 255;
        hp2 = out + (size_t)(jg * 8 + bl) * TT * NN + 4 * k4 - NN;
        hw2 = bl * 1024 + SW(4 * k4);
        f4 = 3 * NTHR + tid; bl = f4 >> 8; k4 = f4 & 255;
        hp3 = out + (size_t)(jg * 8 + bl) * TT * NN + 4 * k4 - NN;
        hw3 = bl * 1024 + SW(4 * k4);
    }
    // this thread's single h-producer: all 4 chunks share k4 = tid & 255
    const int myp = (tid & 255) >> 2;

    // per-lane swizzled read offsets: SW applied to the FULL index (R6/R9 lesson)
    const int kl = 16 * l;
    const int o0 = SW(kl + 0);
    const int o1 = SW(kl + 4);
    const int o2 = SW(kl + 8);
    const int o3 = SW(kl + 12);
    const int wb = rt * 4 * 1024;    // row base (k part lives in o0..o3)
    const int hb = bt * 4 * 1024;

    // padded flag addressing: one 128 B line per flag
    unsigned int* gflags = flags + (size_t)jg * 64 * FSTRIDE;
    unsigned int* mypf   = gflags + (size_t)myp * FSTRIDE;
    unsigned int* mysig  = gflags + (size_t)ig * FSTRIDE;

    __syncthreads();   // w_lds ready

    float acc[4][4];

#define UPART(bb, uv) \
    acc[0][bb] = wir0.x * uv.x + wir0.y * uv.y; \
    acc[1][bb] = wir1.x * uv.x + wir1.y * uv.y; \
    acc[2][bb] = wir2.x * uv.x + wir2.y * uv.y; \
    acc[3][bb] = wir3.x * uv.x + wir3.y * uv.y;

#define DOT(rr, bb, wv, hv) \
    acc[rr][bb] += wv.x*hv.x + wv.y*hv.y + wv.z*hv.z + wv.w*hv.w;

#define QSTEP(o) { \
    float4 wv0 = *reinterpret_cast<const float4*>(&w_lds[wb + 0*1024 + (o)]); \
    float4 wv1 = *reinterpret_cast<const float4*>(&w_lds[wb + 1*1024 + (o)]); \
    float4 wv2 = *reinterpret_cast<const float4*>(&w_lds[wb + 2*1024 + (o)]); \
    float4 wv3 = *reinterpret_cast<const float4*>(&w_lds[wb + 3*1024 + (o)]); \
    float4 hv0 = *reinterpret_cast<const float4*>(&h_stage[hb + 0*1024 + (o)]); \
    float4 hv1 = *reinterpret_cast<const float4*>(&h_stage[hb + 1*1024 + (o)]); \
    float4 hv2 = *reinterpret_cast<const float4*>(&h_stage[hb + 2*1024 + (o)]); \
    float4 hv3 = *reinterpret_cast<const float4*>(&h_stage[hb + 3*1024 + (o)]); \
    DOT(0,0,wv0,hv0) DOT(1,0,wv1,hv0) DOT(2,0,wv2,hv0) DOT(3,0,wv3,hv0) \
    DOT(0,1,wv0,hv1) DOT(1,1,wv1,hv1) DOT(2,1,wv2,hv1) DOT(3,1,wv3,hv1) \
    DOT(0,2,wv0,hv2) DOT(1,2,wv1,hv2) DOT(2,2,wv2,hv2) DOT(3,2,wv3,hv2) \
    DOT(0,3,wv0,hv3) DOT(1,3,wv1,hv3) DOT(2,3,wv2,hv3) DOT(3,3,wv3,hv3) }

    for (int t = 0; t < TT; ++t) {
        // -- issue u loads (overlap the poll) --
        float2 uv0, uv1, uv2, uv3;
        asm volatile("global_load_dwordx2 %0, %1, off" : "=v"(uv0) : "v"(up0));
        asm volatile("global_load_dwordx2 %0, %1, off" : "=v"(uv1) : "v"(up1));
        asm volatile("global_load_dwordx2 %0, %1, off" : "=v"(uv2) : "v"(up2));
        asm volatile("global_load_dwordx2 %0, %1, off" : "=v"(uv3) : "v"(up3));

        float4 h0, h1, h2, h3;
        if (t > 0) {
            // incremental poll: each lane issues its sc1 loads (exec-masked)
            // the iteration its OWN producer signals; loop exits when all
            // lanes have issued. Early loads' IC latency overlaps the
            // straggler wait.
            bool done = false;
            for (;;) {
                bool ready = false;
                if (!done) {
                    unsigned int v = __hip_atomic_load(mypf, __ATOMIC_RELAXED,
                                                       __HIP_MEMORY_SCOPE_AGENT);
                    ready = (v >= (unsigned)t);
                }
                if (ready) {
                    asm volatile("global_load_dwordx4 %0, %1, off sc1" : "=v"(h0) : "v"(hp0));
                    asm volatile("global_load_dwordx4 %0, %1, off sc1" : "=v"(h1) : "v"(hp1));
                    asm volatile("global_load_dwordx4 %0, %1, off sc1" : "=v"(h2) : "v"(hp2));
                    asm volatile("global_load_dwordx4 %0, %1, off sc1" : "=v"(h3) : "v"(hp3));
                    done = true;
                }
                if (__all(done)) break;
                __builtin_amdgcn_s_sleep(1);
            }
        }
        asm volatile("s_waitcnt vmcnt(0)" ::: "memory");  // u and h complete
        __builtin_amdgcn_sched_barrier(0);

        // -- W_in . u partial --
        UPART(0, uv0) UPART(1, uv1) UPART(2, uv2) UPART(3, uv3)

        if (t > 0) {
            *reinterpret_cast<float4*>(&h_stage[hw0]) = h0;
            *reinterpret_cast<float4*>(&h_stage[hw1]) = h1;
            *reinterpret_cast<float4*>(&h_stage[hw2]) = h2;
            *reinterpret_cast<float4*>(&h_stage[hw3]) = h3;
        }
        __syncthreads();   // S1b: h_stage visible to all

        // -- main W.h loop: 32 ds_read_b128 + 256 FMA per thread --
        if (t > 0) {
            QSTEP(o0) QSTEP(o1) QSTEP(o2) QSTEP(o3)
        }

        // -- reduce over lane bits 0..3: DPP (VALU) for xor1/2/8, shfl for 4 --
        #pragma unroll
        for (int rr = 0; rr < 4; ++rr)
            #pragma unroll
            for (int bb = 0; bb < 4; ++bb) {
                float a = acc[rr][bb];
                a = dpp_add_xor1(a);
                a = dpp_add_xor2(a);
                a += __shfl_xor(a, 4);
                a = dpp_add_xor8(a);
                acc[rr][bb] = a;
            }

        // -- select tree: lane m (=l&15) takes output (rr = m&3, bb = m>>2) --
        const int m = l & 15;
        float c00 = (m & 1) ? acc[1][0] : acc[0][0];
        float c01 = (m & 1) ? acc[3][0] : acc[2][0];
        float c10 = (m & 1) ? acc[1][1] : acc[0][1];
        float c11 = (m & 1) ? acc[3][1] : acc[2][1];
        float c20 = (m & 1) ? acc[1][2] : acc[0][2];
        float c21 = (m & 1) ? acc[3][2] : acc[2][2];
        float c30 = (m & 1) ? acc[1][3] : acc[0][3];
        float c31 = (m & 1) ? acc[3][3] : acc[2][3];
        float d0 = (m & 2) ? c01 : c00;
        float d1 = (m & 2) ? c11 : c10;
        float d2 = (m & 2) ? c21 : c20;
        float d3 = (m & 2) ? c31 : c30;
        float e0 = (m & 4) ? d1 : d0;
        float e1 = (m & 4) ? d3 : d2;
        float v  = (m & 8) ? e1 : e0;
        // sum the four 16-lane k-subgroups
        v += __shfl_xor(v, 16);
        v += __shfl_xor(v, 32);

        if (l < 16) {
            float bs = (m & 2) ? ((m & 1) ? b3 : b2) : ((m & 1) ? b1 : b0);
            int rr = m & 3;
            int bb = m >> 2;
            // branch-free fast tanh: tanh(x) = 1 - 2/(e^{2x}+1); |err| ~1e-6
            float x  = v + bs;
            x = fminf(fmaxf(x, -9.f), 9.f);
            float ex = __expf(2.f * x);
            float hval = 1.f - 2.f / (ex + 1.f);
            // h output as atomic EXCHANGE: performed AT the IC, so the
            // vmcnt(0) drain below == IC-visible (closes the R22 race).
            float old = __hip_atomic_exchange(
                out + ((size_t)(bgb + bb) * TT + t) * NN + (n0 + rr),
                hval, __ATOMIC_RELAXED, __HIP_MEMORY_SCOPE_AGENT);
            asm volatile("" :: "v"(old));   // keep the RMW form (no store demotion)
        }

        asm volatile("s_waitcnt vmcnt(0)" ::: "memory");  // h_t performed at IC
        __syncthreads();                                  // S2: WG drained
        if (tid == 0) {
            __hip_atomic_store(mysig, (unsigned)(t + 1),
                               __ATOMIC_RELAXED, __HIP_MEMORY_SCOPE_AGENT);
        }

        up0 += II; up1 += II; up2 += II; up3 += II;
        hp0 += NN; hp1 += NN; hp2 += NN; hp3 += NN;
    }
#undef UPART
#undef DOT
#undef QSTEP
}

extern "C" void kernel_launch(void* const* d_in, const int* in_sizes, int n_in,
                              void* d_out, int out_size, void* d_ws, size_t ws_size,
                              hipStream_t stream) {
    const float* u      = (const float*)d_in[0];
    const float* w_in   = (const float*)d_in[1];
    const float* w      = (const float*)d_in[2];
    const float* w_bias = (const float*)d_in[3];
    float* out          = (float*)d_out;
    unsigned int* flags = (unsigned int*)d_ws;

    // 4 j-groups x 64 flags x 32-dword (128 B) padding = 32 KB, zeroed per call
    hipMemsetAsync(flags, 0, 4 * 64 * FSTRIDE * sizeof(unsigned int), stream);

    // 256 WGs x 512 threads, 96 KB LDS = exactly 1 WG/CU -> co-residency
    // guaranteed, flag spin cannot deadlock.
    esn_kernel<<<dim3(NWG), dim3(NTHR), 0, stream>>>(u, w_in, w, w_bias, out, flags);
}